// Round 5
// baseline (644.625 us; speedup 1.0000x reference)
//
#include <hip/hip_runtime.h>
#include <hip/hip_bf16.h>

// VectorQuantizer on MI355X — runtime-sized, fp32 outputs, fp64-exact argmin.
// Inputs (fp32 buffers, bf16-representable values): z[NT,64], codebook[K,64],
//   cluster_size[K], ema_w[K,64]
// d_out (fp32): quantized[NT*64] | indices[NT] | loss[1] | new_codebook[K*64] |
//   new_cluster_size[K] | new_ema_w[K*64]
// ws (fp32): dw[K*64] | cs[K] | cnorm[K] | loss[1]

#define DECAY 0.99f
#define OMD   0.01f
#define EPSV  1e-5f

typedef __attribute__((ext_vector_type(8))) __bf16 bf16x8;
typedef __attribute__((ext_vector_type(4))) float  float4v;

static __device__ __forceinline__ unsigned short bfbits(float f) {
    __bf16 h = (__bf16)f;
    return __builtin_bit_cast(unsigned short, h);
}
static __device__ __forceinline__ bf16x8 cvt8(float4v a, float4v b) {
    bf16x8 r;
    r[0] = (__bf16)a[0]; r[1] = (__bf16)a[1]; r[2] = (__bf16)a[2]; r[3] = (__bf16)a[3];
    r[4] = (__bf16)b[0]; r[5] = (__bf16)b[1]; r[6] = (__bf16)b[2]; r[7] = (__bf16)b[3];
    return r;
}

// Exact squared distance in fp64 (inputs bf16-valued -> ~exact).
static __device__ double refine_d2(const float* __restrict__ zr,
                                   const float* __restrict__ cb, int idx, int K) {
    if (idx >= K) return 1.0e300;
    const float* cr = cb + (size_t)idx * 64;
    double s = 0.0;
    #pragma unroll 4
    for (int i = 0; i < 16; ++i) {
        float4v zv = *(const float4v*)(zr + i * 4);
        float4v cv = *(const float4v*)(cr + i * 4);
        #pragma unroll
        for (int j = 0; j < 4; ++j) {
            double e = (double)zv[j] - (double)cv[j];
            s = fma(e, e, s);
        }
    }
    return s;
}

__global__ void vq_prep(const float* __restrict__ cb,
                        const float* __restrict__ cs,
                        const float* __restrict__ ema,
                        float* __restrict__ ws, int K) {
    const int KD = K * 64;
    int t = blockIdx.x * 256 + threadIdx.x;
    if (t < KD) ws[t] = DECAY * ema[t];
    if (t < K) {
        ws[KD + t] = DECAY * cs[t];
        const float4v* cp = (const float4v*)(cb + (size_t)t * 64);
        float s = 0.f;
        #pragma unroll
        for (int i = 0; i < 16; ++i) {
            float4v v = cp[i];
            s += v[0] * v[0] + v[1] * v[1] + v[2] * v[2] + v[3] * v[3];
        }
        ws[KD + K + t] = s;
    }
    if (t == 0) ws[KD + 2 * K] = 0.f;
}

// 512 threads = 8 waves; 256 tokens/block (32/wave); codebook staged into LDS
// as bf16 in chunks of 256 codes, row stride 72 shorts (144 B, 16B-aligned).
__launch_bounds__(512)
__global__ void vq_main(const float* __restrict__ z,
                        const float* __restrict__ cb,
                        float* __restrict__ ws,
                        float* __restrict__ out,
                        int NT, int K) {
    __shared__ __align__(16) unsigned short cbs[256 * 72];   // 36 KB
    __shared__ float cns[256];

    const int tid  = threadIdx.x;
    const int lane = tid & 63;
    const int wave = tid >> 6;
    const int col  = lane & 15;
    const int quad = lane >> 4;
    const int wtok0 = blockIdx.x * 256 + wave * 32;
    const int KD = K * 64;
    const float* cnormw = ws + KD + K;

    // ---- B fragments: this wave's 32 tokens (2 groups of 16) ----
    bf16x8 bf0[2], bf1[2];
    #pragma unroll
    for (int g = 0; g < 2; ++g) {
        int tok = wtok0 + g * 16 + col;
        if (tok >= NT) tok = NT - 1;
        const float* zp = z + (size_t)tok * 64 + quad * 8;
        float4v f0 = *(const float4v*)(zp);
        float4v f1 = *(const float4v*)(zp + 4);
        float4v f2 = *(const float4v*)(zp + 32);
        float4v f3 = *(const float4v*)(zp + 36);
        bf0[g] = cvt8(f0, f1);
        bf1[g] = cvt8(f2, f3);
    }

    // per-lane TOP-2 (score, index) per token-group
    float g1[2] = { -3.0e38f, -3.0e38f }, g2v[2] = { -3.0e38f, -3.0e38f };
    int   i1[2] = { 0, 0 },               i2[2] = { 0, 0 };
    const int nchunk = (K + 255) >> 8;

    for (int c = 0; c < nchunk; ++c) {
        #pragma unroll
        for (int i = 0; i < 8; ++i) {
            int f4 = (i * 512 + tid) * 4;
            int row = f4 >> 6, d = f4 & 63;
            int code = c * 256 + row;
            uint2 p;
            if (code < K) {
                float4v v = *(const float4v*)(cb + (size_t)code * 64 + d);
                p.x = (unsigned int)bfbits(v[0]) | ((unsigned int)bfbits(v[1]) << 16);
                p.y = (unsigned int)bfbits(v[2]) | ((unsigned int)bfbits(v[3]) << 16);
            } else { p.x = 0u; p.y = 0u; }
            *(uint2*)(&cbs[row * 72 + d]) = p;
        }
        if (tid < 256) {
            int code = c * 256 + tid;
            cns[tid] = (code < K) ? cnormw[code] : __builtin_inff();
        }
        __syncthreads();

        #pragma unroll 4
        for (int t = 0; t < 16; ++t) {
            const unsigned short* arow = cbs + (t * 16 + col) * 72;
            bf16x8 a0 = *(const bf16x8*)(arow + quad * 8);
            bf16x8 a1 = *(const bf16x8*)(arow + 32 + quad * 8);
            float4v cn = *(const float4v*)(cns + t * 16 + quad * 4);
            const int cbase = c * 256 + t * 16 + quad * 4;
            #pragma unroll
            for (int g = 0; g < 2; ++g) {
                float4v acc = -0.5f * cn;       // score = z.c - |c|^2/2
                acc = __builtin_amdgcn_mfma_f32_16x16x32_bf16(a0, bf0[g], acc, 0, 0, 0);
                acc = __builtin_amdgcn_mfma_f32_16x16x32_bf16(a1, bf1[g], acc, 0, 0, 0);
                #pragma unroll
                for (int r = 0; r < 4; ++r) {
                    float gv = acc[r];
                    int   gi = cbase + r;
                    if (gv > g1[g])      { g2v[g] = g1[g]; i2[g] = i1[g]; g1[g] = gv; i1[g] = gi; }
                    else if (gv > g2v[g]) { g2v[g] = gv; i2[g] = gi; }
                }
            }
        }
        __syncthreads();
    }

    // ---- fp64 exact refinement over per-lane top-2, then cross-quad combine ----
    int ibst[2];
    #pragma unroll
    for (int g = 0; g < 2; ++g) {
        int tok = wtok0 + g * 16 + col;
        if (tok >= NT) tok = NT - 1;
        const float* zr = z + (size_t)tok * 64;
        double s1 = refine_d2(zr, cb, i1[g], K);
        double s2 = refine_d2(zr, cb, i2[g], K);
        double bs; int bi;
        if (s1 < s2 || (s1 == s2 && i1[g] < i2[g])) { bs = s1; bi = i1[g]; }
        else                                        { bs = s2; bi = i2[g]; }
        #pragma unroll
        for (int off = 16; off <= 32; off <<= 1) {
            double os = __shfl_xor(bs, off, 64);
            int    oi = __shfl_xor(bi, off, 64);
            if (os < bs || (os == bs && oi < bi)) { bs = os; bi = oi; }
        }
        ibst[g] = bi;
    }

    const size_t off_idx = (size_t)NT * 64;

    // ---- indices (fp32) ----
    if (lane < 32) {
        int tk = wtok0 + lane;
        if (tk < NT) {
            int ib = (lane < 16) ? ibst[0] : ibst[1];
            out[off_idx + tk] = (float)ib;
        }
    }

    // ---- fused gather + quantized (fp32) + loss + EMA atomics ----
    float* dwacc = ws;
    float* csacc = ws + KD;
    float lsum = 0.f;
    #pragma unroll
    for (int i = 0; i < 8; ++i) {
        int tw  = i * 4 + quad;
        int g   = i >> 2;
        int idx = __shfl(ibst[g], tw & 15, 64);
        int token = wtok0 + tw;
        if (token < NT) {
            int d4 = col * 4;
            float4v zf = *(const float4v*)(z  + (size_t)token * 64 + d4);
            float4v qf = *(const float4v*)(cb + (size_t)idx   * 64 + d4);
            *(float4v*)(out + (size_t)token * 64 + d4) = qf;
            float e0 = zf[0] - qf[0], e1 = zf[1] - qf[1];
            float e2 = zf[2] - qf[2], e3 = zf[3] - qf[3];
            lsum += e0 * e0 + e1 * e1 + e2 * e2 + e3 * e3;
            float* dst = dwacc + (size_t)idx * 64 + d4;
            atomicAdd(dst + 0, OMD * zf[0]);
            atomicAdd(dst + 1, OMD * zf[1]);
            atomicAdd(dst + 2, OMD * zf[2]);
            atomicAdd(dst + 3, OMD * zf[3]);
            if (col == 0) atomicAdd(csacc + idx, OMD);
        }
    }
    #pragma unroll
    for (int off = 1; off < 64; off <<= 1) lsum += __shfl_xor(lsum, off, 64);
    if (lane == 0) atomicAdd(ws + KD + 2 * K, lsum);
}

__global__ void vq_finalize(const float* __restrict__ ws,
                            float* __restrict__ out,
                            int NT, int K) {
    __shared__ float red[16];
    __shared__ float n_sh;
    const int tid = threadIdx.x;
    const int KD = K * 64;
    const float* csa = ws + KD;

    float part = 0.f;
    for (int t = tid; t < K; t += 1024) part += csa[t];
    #pragma unroll
    for (int off = 1; off < 64; off <<= 1) part += __shfl_xor(part, off, 64);
    if ((tid & 63) == 0) red[tid >> 6] = part;
    __syncthreads();
    if (tid == 0) {
        float nn = 0.f;
        #pragma unroll
        for (int i = 0; i < 16; ++i) nn += red[i];
        n_sh = nn;
    }
    __syncthreads();
    const float n = n_sh;

    const size_t off_idx  = (size_t)NT * 64;
    const size_t off_loss = off_idx + NT;
    const size_t off_cb   = off_loss + 1;
    const size_t off_cs   = off_cb + (size_t)KD;
    const size_t off_ema  = off_cs + K;

    for (int t = tid; t < K; t += 1024) {
        float s = csa[t];
        out[off_cs + t] = s;
        const float csn = (s + EPSV) / (n + (float)K * EPSV) * n;
        const float inv = 1.f / csn;
        #pragma unroll 8
        for (int d = 0; d < 64; ++d) {
            float w = ws[(size_t)t * 64 + d];
            out[off_ema + (size_t)t * 64 + d] = w;
            out[off_cb  + (size_t)t * 64 + d] = w * inv;
        }
    }
    if (tid == 0) {
        double denom = (double)NT * 64.0;
        out[off_loss] = (float)((double)ws[KD + 2 * K] / denom);
    }
}

extern "C" void kernel_launch(void* const* d_in, const int* in_sizes, int n_in,
                              void* d_out, int out_size, void* d_ws, size_t ws_size,
                              hipStream_t stream) {
    const float* z   = (const float*)d_in[0];
    const float* cb  = (const float*)d_in[1];
    const float* cs  = (const float*)d_in[2];
    const float* ema = (const float*)d_in[3];
    float* out = (float*)d_out;
    float* ws = (float*)d_ws;

    const int NT = in_sizes[0] / 64;
    const int K  = in_sizes[2];

    int prep_blocks = (K * 64 + 255) / 256;
    vq_prep<<<prep_blocks, 256, 0, stream>>>(cb, cs, ema, ws, K);

    int main_blocks = (NT + 255) / 256;
    vq_main<<<main_blocks, 512, 0, stream>>>(z, cb, ws, out, NT, K);

    vq_finalize<<<1, 1024, 0, stream>>>(ws, out, NT, K);
}

// Round 6
// 486.389 us; speedup vs baseline: 1.3253x; 1.3253x over previous
//
#include <hip/hip_runtime.h>
#include <hip/hip_bf16.h>

// VectorQuantizer on MI355X — R6: atomic-free segment-sum + packed-key scan.
// Inputs (fp32): z[NT,64], codebook[K,64], cluster_size[K], ema_w[K,64]
// d_out (fp32): quantized[NT*64] | indices[NT] | loss[1] | new_codebook[K*64] |
//   new_cluster_size[K] | new_ema_w[K*64]
// ws dwords: cnt[K] | cur[K] | off[K] | sorted[NT] | cnormp[K] | loss | n

#define DECAY 0.99f
#define OMD   0.01f
#define EPSV  1e-5f
#define BIASF 192.0f    // folded into MFMA acc init: score' = 192 + z.c - |c|^2/2 > 0

typedef __attribute__((ext_vector_type(8))) __bf16 bf16x8;
typedef __attribute__((ext_vector_type(4))) float  float4v;

static __device__ __forceinline__ unsigned short bfbits(float f) {
    __bf16 h = (__bf16)f;
    return __builtin_bit_cast(unsigned short, h);
}
static __device__ __forceinline__ bf16x8 cvt8(float4v a, float4v b) {
    bf16x8 r;
    r[0] = (__bf16)a[0]; r[1] = (__bf16)a[1]; r[2] = (__bf16)a[2]; r[3] = (__bf16)a[3];
    r[4] = (__bf16)b[0]; r[5] = (__bf16)b[1]; r[6] = (__bf16)b[2]; r[7] = (__bf16)b[3];
    return r;
}

// Exact squared distance in fp64 (inputs bf16-valued -> exact).
static __device__ double refine_d2(const float* __restrict__ zr,
                                   const float* __restrict__ cb, int idx, int K) {
    if (idx >= K) return 1.0e300;
    const float* cr = cb + (size_t)idx * 64;
    double s = 0.0;
    #pragma unroll 4
    for (int i = 0; i < 16; ++i) {
        float4v zv = *(const float4v*)(zr + i * 4);
        float4v cv = *(const float4v*)(cr + i * 4);
        #pragma unroll
        for (int j = 0; j < 4; ++j) {
            double e = (double)zv[j] - (double)cv[j];
            s = fma(e, e, s);
        }
    }
    return s;
}

// key low 8 bits = per-lane candidate number iter = (c<<6)|(t<<2)|r
static __device__ __forceinline__ int dec_idx(unsigned key, int quad) {
    int iter = key & 255;
    return ((iter >> 6) << 8) + (((iter >> 2) & 15) << 4) + (quad << 2) + (iter & 3);
}

__global__ void vq_prep(const float* __restrict__ cb,
                        float* __restrict__ wsf, int* __restrict__ wsi,
                        int K, int NT) {
    int t = blockIdx.x * 256 + threadIdx.x;
    if (t < K) {
        wsi[t] = 0;                               // cnt
        const float4v* cp = (const float4v*)(cb + (size_t)t * 64);
        float s = 0.f;
        #pragma unroll
        for (int i = 0; i < 16; ++i) {
            float4v v = cp[i];
            s += v[0] * v[0] + v[1] * v[1] + v[2] * v[2] + v[3] * v[3];
        }
        wsf[3 * K + NT + t] = BIASF - 0.5f * s;   // cnormp
    }
    if (t == 0) wsf[4 * K + NT] = 0.f;            // loss
}

// 512 threads = 8 waves; 256 tokens/block (32/wave); codebook bf16 in LDS,
// chunks of 256 codes, row stride 72 shorts (144 B, 16B-aligned).
__launch_bounds__(512)
__global__ void vq_main(const float* __restrict__ z,
                        const float* __restrict__ cb,
                        float* __restrict__ wsf, int* __restrict__ wsi,
                        float* __restrict__ out,
                        int NT, int K) {
    __shared__ __align__(16) unsigned short cbs[256 * 72];   // 36 KB
    __shared__ float cns[256];
    __shared__ int hist[1024];

    const int tid  = threadIdx.x;
    const int lane = tid & 63;
    const int wave = tid >> 6;
    const int col  = lane & 15;
    const int quad = lane >> 4;
    const int wtok0 = blockIdx.x * 256 + wave * 32;
    const float* cnormp = wsf + 3 * K + NT;
    const bool smallK = (K <= 1024);

    for (int i = tid; i < 1024; i += 512) hist[i] = 0;

    // ---- B fragments: this wave's 32 tokens (2 groups of 16) ----
    bf16x8 bf0[2], bf1[2];
    #pragma unroll
    for (int g = 0; g < 2; ++g) {
        int tok = wtok0 + g * 16 + col;
        if (tok >= NT) tok = NT - 1;
        const float* zp = z + (size_t)tok * 64 + quad * 8;
        float4v f0 = *(const float4v*)(zp);
        float4v f1 = *(const float4v*)(zp + 4);
        float4v f2 = *(const float4v*)(zp + 32);
        float4v f3 = *(const float4v*)(zp + 36);
        bf0[g] = cvt8(f0, f1);
        bf1[g] = cvt8(f2, f3);
    }

    // per-lane top-2 packed keys (score bits | candidate#), per token-group
    unsigned k1[2] = { 0u, 0u }, k2[2] = { 0u, 0u };
    const unsigned kmask = 0xFFFFFF00u;
    const int nchunk = (K + 255) >> 8;

    for (int c = 0; c < nchunk; ++c) {
        #pragma unroll
        for (int i = 0; i < 8; ++i) {
            int f4 = (i * 512 + tid) * 4;
            int row = f4 >> 6, d = f4 & 63;
            int code = c * 256 + row;
            uint2 p;
            if (code < K) {
                float4v v = *(const float4v*)(cb + (size_t)code * 64 + d);
                p.x = (unsigned int)bfbits(v[0]) | ((unsigned int)bfbits(v[1]) << 16);
                p.y = (unsigned int)bfbits(v[2]) | ((unsigned int)bfbits(v[3]) << 16);
            } else { p.x = 0u; p.y = 0u; }
            *(uint2*)(&cbs[row * 72 + d]) = p;
        }
        if (tid < 256) {
            int code = c * 256 + tid;
            cns[tid] = (code < K) ? cnormp[code] : 0.0f;   // pad -> tiny key
        }
        __syncthreads();

        #pragma unroll 4
        for (int t = 0; t < 16; ++t) {
            const unsigned short* arow = cbs + (t * 16 + col) * 72;
            bf16x8 a0 = *(const bf16x8*)(arow + quad * 8);
            bf16x8 a1 = *(const bf16x8*)(arow + 32 + quad * 8);
            float4v cni = *(const float4v*)(cns + t * 16 + quad * 4);
            const int iterbase = (c << 6) | (t << 2);
            #pragma unroll
            for (int g = 0; g < 2; ++g) {
                float4v acc = cni;              // = BIAS - |c|^2/2
                acc = __builtin_amdgcn_mfma_f32_16x16x32_bf16(a0, bf0[g], acc, 0, 0, 0);
                acc = __builtin_amdgcn_mfma_f32_16x16x32_bf16(a1, bf1[g], acc, 0, 0, 0);
                #pragma unroll
                for (int r = 0; r < 4; ++r) {
                    unsigned kb = (__float_as_uint(acc[r]) & kmask) | (unsigned)(iterbase + r);
                    unsigned lo = k2[g] > kb ? k2[g] : kb;       // max(k2,kb)
                    k2[g] = k1[g] < lo ? k1[g] : lo;             // min(k1,.) -> med3
                    k1[g] = k1[g] > kb ? k1[g] : kb;             // max(k1,kb)
                }
            }
        }
        __syncthreads();
    }

    // ---- fp64 exact refinement over per-lane top-2, cross-quad combine ----
    int ibst[2];
    #pragma unroll
    for (int g = 0; g < 2; ++g) {
        int tok = wtok0 + g * 16 + col;
        if (tok >= NT) tok = NT - 1;
        const float* zr = z + (size_t)tok * 64;
        int ia = dec_idx(k1[g], quad), ib2 = dec_idx(k2[g], quad);
        double s1 = refine_d2(zr, cb, ia, K);
        double s2 = refine_d2(zr, cb, ib2, K);
        double bs; int bi;
        if (s1 < s2 || (s1 == s2 && ia < ib2)) { bs = s1; bi = ia; }
        else                                    { bs = s2; bi = ib2; }
        #pragma unroll
        for (int off = 16; off <= 32; off <<= 1) {
            double os = __shfl_xor(bs, off, 64);
            int    oi = __shfl_xor(bi, off, 64);
            if (os < bs || (os == bs && oi < bi)) { bs = os; bi = oi; }
        }
        ibst[g] = bi;
    }

    const size_t off_idx = (size_t)NT * 64;

    // ---- indices (fp32) + histogram ----
    if (lane < 32) {
        int tk = wtok0 + lane;
        if (tk < NT) {
            int ib = (lane < 16) ? ibst[0] : ibst[1];
            out[off_idx + tk] = (float)ib;
            if (smallK) atomicAdd(&hist[ib], 1);
            else        atomicAdd(&wsi[ib], 1);
        }
    }

    // ---- quantized gather + loss (no dw atomics!) ----
    float lsum = 0.f;
    #pragma unroll
    for (int i = 0; i < 8; ++i) {
        int tw  = i * 4 + quad;
        int g   = i >> 2;
        int idx = __shfl(ibst[g], tw & 15, 64);
        int token = wtok0 + tw;
        if (token < NT) {
            int d4 = col * 4;
            float4v zf = *(const float4v*)(z  + (size_t)token * 64 + d4);
            float4v qf = *(const float4v*)(cb + (size_t)idx   * 64 + d4);
            *(float4v*)(out + (size_t)token * 64 + d4) = qf;
            float e0 = zf[0] - qf[0], e1 = zf[1] - qf[1];
            float e2 = zf[2] - qf[2], e3 = zf[3] - qf[3];
            lsum += e0 * e0 + e1 * e1 + e2 * e2 + e3 * e3;
        }
    }
    #pragma unroll
    for (int off = 1; off < 64; off <<= 1) lsum += __shfl_xor(lsum, off, 64);
    if (lane == 0) atomicAdd(wsf + 4 * K + NT, lsum);

    // ---- flush block histogram ----
    __syncthreads();
    if (smallK) {
        for (int k = tid; k < K; k += 512) {
            int c = hist[k];
            if (c) atomicAdd(&wsi[k], c);
        }
    }
}

// Single block: exclusive prefix of cnt -> off/cur, n = sum new_cluster_size, loss out.
__global__ void vq_scan(const float* __restrict__ cs,
                        float* __restrict__ wsf, int* __restrict__ wsi,
                        float* __restrict__ out, int NT, int K) {
    __shared__ int sc[1024];
    __shared__ float red[16];
    const int tid = threadIdx.x;

    int carry = 0;
    float cs_part = 0.f;
    int   cnt_part = 0;
    for (int base = 0; base < K; base += 1024) {
        int k = base + tid;
        int c = (k < K) ? wsi[k] : 0;
        if (k < K) { cs_part += cs[k]; cnt_part += c; }
        sc[tid] = c;
        __syncthreads();
        for (int s = 1; s < 1024; s <<= 1) {
            int v = (tid >= s) ? sc[tid - s] : 0;
            __syncthreads();
            sc[tid] += v;
            __syncthreads();
        }
        int incl = sc[tid];
        int excl = incl - c + carry;
        if (k < K) { wsi[2 * K + k] = excl; wsi[K + k] = excl; }  // off, cur
        carry += sc[1023];
        __syncthreads();
    }

    // n = sum(DECAY*cs + OMD*cnt)
    float part = DECAY * cs_part + OMD * (float)cnt_part;
    #pragma unroll
    for (int off = 1; off < 64; off <<= 1) part += __shfl_xor(part, off, 64);
    if ((tid & 63) == 0) red[tid >> 6] = part;
    __syncthreads();
    if (tid == 0) {
        float nn = 0.f;
        #pragma unroll
        for (int i = 0; i < 16; ++i) nn += red[i];
        wsf[4 * K + NT + 1] = nn;
        out[(size_t)NT * 64 + NT] = wsf[4 * K + NT] / ((float)NT * 64.0f);  // loss
    }
}

__global__ void vq_scatter(const float* __restrict__ out_idx,
                           int* __restrict__ wsi, int NT, int K) {
    int t = blockIdx.x * 256 + threadIdx.x;
    if (t < NT) {
        int idx = (int)out_idx[t];
        int pos = atomicAdd(&wsi[K + idx], 1);       // cur
        wsi[3 * K + pos] = t;                        // sorted
    }
}

// One block (4 waves, 256 thr) per code: coalesced segment sum + finalize.
__global__ void vq_gather(const float* __restrict__ z,
                          const float* __restrict__ cs,
                          const float* __restrict__ ema,
                          const float* __restrict__ wsf,
                          const int* __restrict__ wsi,
                          float* __restrict__ out, int NT, int K) {
    __shared__ float part[4][64];
    const int k    = blockIdx.x;
    const int lane = threadIdx.x & 63;
    const int wave = threadIdx.x >> 6;
    const int cnt  = wsi[k];
    const int off  = wsi[2 * K + k];
    const int* sorted = wsi + 3 * K;

    float sum = 0.f;
    for (int i = off + wave; i < off + cnt; i += 4) {
        int tok = sorted[i];
        sum += z[(size_t)tok * 64 + lane];
    }
    part[wave][lane] = sum;
    __syncthreads();
    if (wave == 0) {
        float s = part[0][lane] + part[1][lane] + part[2][lane] + part[3][lane];
        float dw = DECAY * ema[(size_t)k * 64 + lane] + OMD * s;
        float ncs = DECAY * cs[k] + OMD * (float)cnt;
        float n = wsf[4 * K + NT + 1];
        float csn = (ncs + EPSV) / (n + (float)K * EPSV) * n;
        const size_t off_cb  = (size_t)NT * 64 + NT + 1;
        const size_t off_cs  = off_cb + (size_t)K * 64;
        const size_t off_ema = off_cs + K;
        out[off_ema + (size_t)k * 64 + lane] = dw;
        out[off_cb  + (size_t)k * 64 + lane] = dw / csn;
        if (lane == 0) out[off_cs + k] = ncs;
    }
}

extern "C" void kernel_launch(void* const* d_in, const int* in_sizes, int n_in,
                              void* d_out, int out_size, void* d_ws, size_t ws_size,
                              hipStream_t stream) {
    const float* z   = (const float*)d_in[0];
    const float* cb  = (const float*)d_in[1];
    const float* cs  = (const float*)d_in[2];
    const float* ema = (const float*)d_in[3];
    float* out = (float*)d_out;
    float* wsf = (float*)d_ws;
    int*   wsi = (int*)d_ws;

    const int NT = in_sizes[0] / 64;
    const int K  = in_sizes[2];

    vq_prep<<<(K + 255) / 256, 256, 0, stream>>>(cb, wsf, wsi, K, NT);
    vq_main<<<(NT + 255) / 256, 512, 0, stream>>>(z, cb, wsf, wsi, out, NT, K);
    vq_scan<<<1, 1024, 0, stream>>>(cs, wsf, wsi, out, NT, K);
    vq_scatter<<<(NT + 255) / 256, 256, 0, stream>>>(out + (size_t)NT * 64, wsi, NT, K);
    vq_gather<<<K, 256, 0, stream>>>(z, cs, ema, wsf, wsi, out, NT, K);
}

// Round 7
// 272.124 us; speedup vs baseline: 2.3689x; 1.7874x over previous
//
#include <hip/hip_runtime.h>
#include <hip/hip_bf16.h>

// VectorQuantizer on MI355X — R7: balanced segmented reduction for dw.
// Inputs (fp32): z[NT,64], codebook[K,64], cluster_size[K], ema_w[K,64]
// d_out (fp32): quantized[NT*64] | indices[NT] | loss[1] | new_codebook[K*64] |
//   new_cluster_size[K] | new_ema_w[K*64]
// ws dwords: cnt[K] | cur[K] | off[K] | sorted[NT] | dwacc[K*64] | cnormp[K] | loss | n

#define DECAY 0.99f
#define OMD   0.01f
#define EPSV  1e-5f
#define BIASF 192.0f    // folded into MFMA acc init: score' = 192 + z.c - |c|^2/2 > 0

typedef __attribute__((ext_vector_type(8))) __bf16 bf16x8;
typedef __attribute__((ext_vector_type(4))) float  float4v;

static __device__ __forceinline__ unsigned short bfbits(float f) {
    __bf16 h = (__bf16)f;
    return __builtin_bit_cast(unsigned short, h);
}
static __device__ __forceinline__ bf16x8 cvt8(float4v a, float4v b) {
    bf16x8 r;
    r[0] = (__bf16)a[0]; r[1] = (__bf16)a[1]; r[2] = (__bf16)a[2]; r[3] = (__bf16)a[3];
    r[4] = (__bf16)b[0]; r[5] = (__bf16)b[1]; r[6] = (__bf16)b[2]; r[7] = (__bf16)b[3];
    return r;
}

// Exact squared distance in fp64 (inputs bf16-valued -> exact).
static __device__ double refine_d2(const float* __restrict__ zr,
                                   const float* __restrict__ cb, int idx, int K) {
    if (idx >= K) return 1.0e300;
    const float* cr = cb + (size_t)idx * 64;
    double s = 0.0;
    #pragma unroll 4
    for (int i = 0; i < 16; ++i) {
        float4v zv = *(const float4v*)(zr + i * 4);
        float4v cv = *(const float4v*)(cr + i * 4);
        #pragma unroll
        for (int j = 0; j < 4; ++j) {
            double e = (double)zv[j] - (double)cv[j];
            s = fma(e, e, s);
        }
    }
    return s;
}

// key low 8 bits = per-lane candidate number iter = (c<<6)|(t<<2)|r
static __device__ __forceinline__ int dec_idx(unsigned key, int quad) {
    int iter = key & 255;
    return ((iter >> 6) << 8) + (((iter >> 2) & 15) << 4) + (quad << 2) + (iter & 3);
}

__global__ void vq_prep(const float* __restrict__ cb,
                        float* __restrict__ wsf, int* __restrict__ wsi,
                        int K, int NT) {
    const int KD = K * 64;
    int t = blockIdx.x * 256 + threadIdx.x;      // grid covers K*64
    if (t < KD) wsf[3 * K + NT + t] = 0.f;       // dwacc zero-init
    if (t < K) {
        wsi[t] = 0;                               // cnt
        const float4v* cp = (const float4v*)(cb + (size_t)t * 64);
        float s = 0.f;
        #pragma unroll
        for (int i = 0; i < 16; ++i) {
            float4v v = cp[i];
            s += v[0] * v[0] + v[1] * v[1] + v[2] * v[2] + v[3] * v[3];
        }
        wsf[3 * K + NT + KD + t] = BIASF - 0.5f * s;   // cnormp
    }
    if (t == 0) wsf[3 * K + NT + KD + K] = 0.f;   // loss
}

// 512 threads = 8 waves; 256 tokens/block (32/wave); codebook bf16 in LDS.
__launch_bounds__(512)
__global__ void vq_main(const float* __restrict__ z,
                        const float* __restrict__ cb,
                        float* __restrict__ wsf, int* __restrict__ wsi,
                        float* __restrict__ out,
                        int NT, int K) {
    __shared__ __align__(16) unsigned short cbs[256 * 72];   // 36 KB
    __shared__ float cns[256];
    __shared__ int hist[1024];

    const int tid  = threadIdx.x;
    const int lane = tid & 63;
    const int wave = tid >> 6;
    const int col  = lane & 15;
    const int quad = lane >> 4;
    const int wtok0 = blockIdx.x * 256 + wave * 32;
    const int KD = K * 64;
    const float* cnormp = wsf + 3 * K + NT + KD;
    float* lossp = wsf + 3 * K + NT + KD + K;
    const bool smallK = (K <= 1024);

    for (int i = tid; i < 1024; i += 512) hist[i] = 0;

    bf16x8 bf0[2], bf1[2];
    #pragma unroll
    for (int g = 0; g < 2; ++g) {
        int tok = wtok0 + g * 16 + col;
        if (tok >= NT) tok = NT - 1;
        const float* zp = z + (size_t)tok * 64 + quad * 8;
        float4v f0 = *(const float4v*)(zp);
        float4v f1 = *(const float4v*)(zp + 4);
        float4v f2 = *(const float4v*)(zp + 32);
        float4v f3 = *(const float4v*)(zp + 36);
        bf0[g] = cvt8(f0, f1);
        bf1[g] = cvt8(f2, f3);
    }

    unsigned k1[2] = { 0u, 0u }, k2[2] = { 0u, 0u };
    const unsigned kmask = 0xFFFFFF00u;
    const int nchunk = (K + 255) >> 8;

    for (int c = 0; c < nchunk; ++c) {
        #pragma unroll
        for (int i = 0; i < 8; ++i) {
            int f4 = (i * 512 + tid) * 4;
            int row = f4 >> 6, d = f4 & 63;
            int code = c * 256 + row;
            uint2 p;
            if (code < K) {
                float4v v = *(const float4v*)(cb + (size_t)code * 64 + d);
                p.x = (unsigned int)bfbits(v[0]) | ((unsigned int)bfbits(v[1]) << 16);
                p.y = (unsigned int)bfbits(v[2]) | ((unsigned int)bfbits(v[3]) << 16);
            } else { p.x = 0u; p.y = 0u; }
            *(uint2*)(&cbs[row * 72 + d]) = p;
        }
        if (tid < 256) {
            int code = c * 256 + tid;
            cns[tid] = (code < K) ? cnormp[code] : 0.0f;
        }
        __syncthreads();

        #pragma unroll 4
        for (int t = 0; t < 16; ++t) {
            const unsigned short* arow = cbs + (t * 16 + col) * 72;
            bf16x8 a0 = *(const bf16x8*)(arow + quad * 8);
            bf16x8 a1 = *(const bf16x8*)(arow + 32 + quad * 8);
            float4v cni = *(const float4v*)(cns + t * 16 + quad * 4);
            const int iterbase = (c << 6) | (t << 2);
            #pragma unroll
            for (int g = 0; g < 2; ++g) {
                float4v acc = cni;              // = BIAS - |c|^2/2
                acc = __builtin_amdgcn_mfma_f32_16x16x32_bf16(a0, bf0[g], acc, 0, 0, 0);
                acc = __builtin_amdgcn_mfma_f32_16x16x32_bf16(a1, bf1[g], acc, 0, 0, 0);
                #pragma unroll
                for (int r = 0; r < 4; ++r) {
                    unsigned kb = (__float_as_uint(acc[r]) & kmask) | (unsigned)(iterbase + r);
                    unsigned lo = k2[g] > kb ? k2[g] : kb;
                    k2[g] = k1[g] < lo ? k1[g] : lo;
                    k1[g] = k1[g] > kb ? k1[g] : kb;
                }
            }
        }
        __syncthreads();
    }

    int ibst[2];
    #pragma unroll
    for (int g = 0; g < 2; ++g) {
        int tok = wtok0 + g * 16 + col;
        if (tok >= NT) tok = NT - 1;
        const float* zr = z + (size_t)tok * 64;
        int ia = dec_idx(k1[g], quad), ib2 = dec_idx(k2[g], quad);
        double s1 = refine_d2(zr, cb, ia, K);
        double s2 = refine_d2(zr, cb, ib2, K);
        double bs; int bi;
        if (s1 < s2 || (s1 == s2 && ia < ib2)) { bs = s1; bi = ia; }
        else                                    { bs = s2; bi = ib2; }
        #pragma unroll
        for (int off = 16; off <= 32; off <<= 1) {
            double os = __shfl_xor(bs, off, 64);
            int    oi = __shfl_xor(bi, off, 64);
            if (os < bs || (os == bs && oi < bi)) { bs = os; bi = oi; }
        }
        ibst[g] = bi;
    }

    const size_t off_idx = (size_t)NT * 64;

    if (lane < 32) {
        int tk = wtok0 + lane;
        if (tk < NT) {
            int ib = (lane < 16) ? ibst[0] : ibst[1];
            out[off_idx + tk] = (float)ib;
            if (smallK) atomicAdd(&hist[ib], 1);
            else        atomicAdd(&wsi[ib], 1);
        }
    }

    float lsum = 0.f;
    #pragma unroll
    for (int i = 0; i < 8; ++i) {
        int tw  = i * 4 + quad;
        int g   = i >> 2;
        int idx = __shfl(ibst[g], tw & 15, 64);
        int token = wtok0 + tw;
        if (token < NT) {
            int d4 = col * 4;
            float4v zf = *(const float4v*)(z  + (size_t)token * 64 + d4);
            float4v qf = *(const float4v*)(cb + (size_t)idx   * 64 + d4);
            *(float4v*)(out + (size_t)token * 64 + d4) = qf;
            float e0 = zf[0] - qf[0], e1 = zf[1] - qf[1];
            float e2 = zf[2] - qf[2], e3 = zf[3] - qf[3];
            lsum += e0 * e0 + e1 * e1 + e2 * e2 + e3 * e3;
        }
    }
    #pragma unroll
    for (int off = 1; off < 64; off <<= 1) lsum += __shfl_xor(lsum, off, 64);
    if (lane == 0) atomicAdd(lossp, lsum);

    __syncthreads();
    if (smallK) {
        for (int k = tid; k < K; k += 512) {
            int c = hist[k];
            if (c) atomicAdd(&wsi[k], c);
        }
    }
}

// Single block: exclusive prefix of cnt -> off/cur, n, loss output.
__global__ void vq_scan(const float* __restrict__ cs,
                        float* __restrict__ wsf, int* __restrict__ wsi,
                        float* __restrict__ out, int NT, int K) {
    __shared__ int sc[1024];
    __shared__ float red[16];
    const int tid = threadIdx.x;
    const int KD = K * 64;

    int carry = 0;
    float cs_part = 0.f;
    int   cnt_part = 0;
    for (int base = 0; base < K; base += 1024) {
        int k = base + tid;
        int c = (k < K) ? wsi[k] : 0;
        if (k < K) { cs_part += cs[k]; cnt_part += c; }
        sc[tid] = c;
        __syncthreads();
        for (int s = 1; s < 1024; s <<= 1) {
            int v = (tid >= s) ? sc[tid - s] : 0;
            __syncthreads();
            sc[tid] += v;
            __syncthreads();
        }
        int incl = sc[tid];
        int excl = incl - c + carry;
        if (k < K) { wsi[2 * K + k] = excl; wsi[K + k] = excl; }
        carry += sc[1023];
        __syncthreads();
    }

    float part = DECAY * cs_part + OMD * (float)cnt_part;
    #pragma unroll
    for (int off = 1; off < 64; off <<= 1) part += __shfl_xor(part, off, 64);
    if ((tid & 63) == 0) red[tid >> 6] = part;
    __syncthreads();
    if (tid == 0) {
        float nn = 0.f;
        #pragma unroll
        for (int i = 0; i < 16; ++i) nn += red[i];
        wsf[3 * K + NT + KD + K + 1] = nn;                                // n
        out[(size_t)NT * 64 + NT] = wsf[3 * K + NT + KD + K] / ((float)NT * 64.0f);
    }
}

__global__ void vq_scatter(const float* __restrict__ out_idx,
                           int* __restrict__ wsi, int NT, int K) {
    int t = blockIdx.x * 256 + threadIdx.x;
    if (t < NT) {
        int idx = (int)out_idx[t];
        int pos = atomicAdd(&wsi[K + idx], 1);
        wsi[3 * K + pos] = t;
    }
}

// Balanced segmented reduction: one wave per 64 consecutive sorted tokens.
// Codes are non-decreasing along sorted[]; walk runs via ballot, 4-way MLP row
// loads, one coalesced 64-lane atomicAdd per run into dwacc.
__launch_bounds__(256)
__global__ void vq_seg(const float* __restrict__ z,
                       const float* __restrict__ out_idx,
                       const int* __restrict__ sorted,
                       float* __restrict__ dwacc, int NT) {
    const int gw   = blockIdx.x * 4 + (threadIdx.x >> 6);
    const int lane = threadIdx.x & 63;
    const int base = gw * 64;
    if (base >= NT) return;
    const int n = (NT - base < 64) ? (NT - base) : 64;

    int tok = 0, code = 0x7fffffff;
    if (lane < n) { tok = sorted[base + lane]; code = (int)out_idx[tok]; }

    int j = 0;
    while (j < n) {
        const int c = __shfl(code, j, 64);
        unsigned long long neq = __ballot(code != c);
        neq &= ~((j == 0) ? 0ULL : ((1ULL << j) - 1ULL));
        int run_end = (neq == 0ULL) ? 64 : (__ffsll((long long)neq) - 1);
        if (run_end > n) run_end = n;

        float acc = 0.f;
        int i = j;
        for (; i + 4 <= run_end; i += 4) {
            int t0 = __shfl(tok, i, 64),   t1 = __shfl(tok, i + 1, 64);
            int t2 = __shfl(tok, i + 2, 64), t3 = __shfl(tok, i + 3, 64);
            float a0 = z[(size_t)t0 * 64 + lane];
            float a1 = z[(size_t)t1 * 64 + lane];
            float a2 = z[(size_t)t2 * 64 + lane];
            float a3 = z[(size_t)t3 * 64 + lane];
            acc += (a0 + a1) + (a2 + a3);
        }
        for (; i < run_end; ++i) {
            int t0 = __shfl(tok, i, 64);
            acc += z[(size_t)t0 * 64 + lane];
        }
        atomicAdd(&dwacc[(size_t)c * 64 + lane], OMD * acc);
        j = run_end;
    }
}

// Final: combine accumulators -> new_ema_w, new_codebook, new_cluster_size.
__global__ void vq_final(const float* __restrict__ cs,
                         const float* __restrict__ ema,
                         const float* __restrict__ wsf,
                         const int* __restrict__ wsi,
                         float* __restrict__ out, int NT, int K) {
    const int KD = K * 64;
    int t = blockIdx.x * 256 + threadIdx.x;
    if (t >= KD) return;
    const int k = t >> 6;
    const float n = wsf[3 * K + NT + KD + K + 1];
    const float dw = DECAY * ema[t] + wsf[3 * K + NT + t];
    const float ncs = DECAY * cs[k] + OMD * (float)wsi[k];
    const float csn = (ncs + EPSV) / (n + (float)K * EPSV) * n;
    const size_t off_cb  = (size_t)NT * 64 + NT + 1;
    const size_t off_cs  = off_cb + (size_t)KD;
    const size_t off_ema = off_cs + K;
    out[off_cb  + t] = dw / csn;
    out[off_ema + t] = dw;
    if ((t & 63) == 0) out[off_cs + k] = ncs;
}

extern "C" void kernel_launch(void* const* d_in, const int* in_sizes, int n_in,
                              void* d_out, int out_size, void* d_ws, size_t ws_size,
                              hipStream_t stream) {
    const float* z   = (const float*)d_in[0];
    const float* cb  = (const float*)d_in[1];
    const float* cs  = (const float*)d_in[2];
    const float* ema = (const float*)d_in[3];
    float* out = (float*)d_out;
    float* wsf = (float*)d_ws;
    int*   wsi = (int*)d_ws;

    const int NT = in_sizes[0] / 64;
    const int K  = in_sizes[2];
    const int KD = K * 64;

    vq_prep<<<(KD + 255) / 256, 256, 0, stream>>>(cb, wsf, wsi, K, NT);
    vq_main<<<(NT + 255) / 256, 512, 0, stream>>>(z, cb, wsf, wsi, out, NT, K);
    vq_scan<<<1, 1024, 0, stream>>>(cs, wsf, wsi, out, NT, K);
    vq_scatter<<<(NT + 255) / 256, 256, 0, stream>>>(out + (size_t)NT * 64, wsi, NT, K);
    vq_seg<<<(NT + 255) / 256, 256, 0, stream>>>(z, out + (size_t)NT * 64,
                                                 wsi + 3 * K, wsf + 3 * K + NT, NT);
    vq_final<<<(KD + 255) / 256, 256, 0, stream>>>(cs, ema, wsf, wsi, out, NT, K);
}